// Round 5
// baseline (405.120 us; speedup 1.0000x reference)
//
#include <hip/hip_runtime.h>
#include <hip/hip_bf16.h>
#include <cstdint>
#include <cstddef>

#define DI __device__ __forceinline__

typedef __attribute__((ext_vector_type(8))) short short8;
typedef __attribute__((ext_vector_type(4))) float f32x4;

static constexpr int Bb = 8192, Dd = 512, Hh = 1024;

DI short f2b(float f) {
  union { __hip_bfloat16 h; short s; } u;
  u.h = __float2bfloat16(f);
  return u.s;
}

// fast sigmoid/tanh: v_exp + v_rcp (1-ulp rcp; output checked at bf16 level)
DI float sigm(float x) {
  float e = __builtin_amdgcn_exp2f(-1.4426950408889634f * x);
  return __builtin_amdgcn_rcpf(1.0f + e);
}
DI float tanh_(float x) {
  float xc = fminf(fmaxf(x, -20.0f), 20.0f);
  float e = __builtin_amdgcn_exp2f(-2.8853900817779268f * xc);  // exp(-2x)
  return (1.0f - e) * __builtin_amdgcn_rcpf(1.0f + e);
}

DI void gload16(const void* g, void* l) {
  __builtin_amdgcn_global_load_lds(
      (const __attribute__((address_space(1))) uint32_t*)g,
      (__attribute__((address_space(3))) uint32_t*)l, 16, 0, 0);
}

// ---------------- prep kernels ----------------

__global__ void conv_A0(const float* __restrict__ x, const float* __restrict__ h0,
                        const float* __restrict__ m0, short* __restrict__ A0) {
  const int row = blockIdx.x, t = threadIdx.x;  // block=192
  float v[8];
  if (t < 64) {
    const float4* p = (const float4*)(x + (size_t)row * Dd + t * 8);
    float4 a = p[0], b = p[1];
    v[0] = a.x; v[1] = a.y; v[2] = a.z; v[3] = a.w;
    v[4] = b.x; v[5] = b.y; v[6] = b.z; v[7] = b.w;
  } else {
    const int j = t * 8 - 512;
    const float4* ph = (const float4*)(h0 + (size_t)row * Hh + j);
    const float4* pm = (const float4*)(m0 + (size_t)row * Hh + j);
    float4 a = ph[0], b = ph[1], ma = pm[0], mb = pm[1];
    v[0] = a.x * ma.x; v[1] = a.y * ma.y; v[2] = a.z * ma.z; v[3] = a.w * ma.w;
    v[4] = b.x * mb.x; v[5] = b.y * mb.y; v[6] = b.z * mb.z; v[7] = b.w * mb.w;
  }
  short8 o;
  #pragma unroll
  for (int q = 0; q < 8; q++) o[q] = f2b(v[q]);
  *(short8*)(A0 + (size_t)row * 1536 + t * 8) = o;
}

__global__ void conv_A1hi(const float* __restrict__ h1, const float* __restrict__ m1,
                          short* __restrict__ A1) {
  const int row = blockIdx.x, t = threadIdx.x;  // block=128
  const int j = t * 8;
  const float4* ph = (const float4*)(h1 + (size_t)row * Hh + j);
  const float4* pm = (const float4*)(m1 + (size_t)row * Hh + j);
  float4 a = ph[0], b = ph[1], ma = pm[0], mb = pm[1];
  float v[8] = {a.x * ma.x, a.y * ma.y, a.z * ma.z, a.w * ma.w,
                b.x * mb.x, b.y * mb.y, b.z * mb.z, b.w * mb.w};
  short8 o;
  #pragma unroll
  for (int q = 0; q < 8; q++) o[q] = f2b(v[q]);
  *(short8*)(A1 + (size_t)row * 2048 + 1024 + j) = o;
}

// 4-gate fused transpose+convert
__global__ void transpose_conv4(const float* __restrict__ s0, const float* __restrict__ s1,
                                const float* __restrict__ s2, const float* __restrict__ s3,
                                short* __restrict__ dst, int N, int K) {
  __shared__ float t[64][65];
  const int g = blockIdx.z;
  const float* src = (g == 0) ? s0 : (g == 1) ? s1 : (g == 2) ? s2 : s3;
  const int k0 = blockIdx.x * 64, n0 = blockIdx.y * 64;
  const int tid = threadIdx.x;           // 256
  const int r = tid >> 2, c0 = (tid & 3) * 16;
  const float* s = src + (size_t)(k0 + r) * N + n0 + c0;
  #pragma unroll
  for (int q = 0; q < 16; q += 4) {
    float4 v = *(const float4*)(s + q);
    t[r][c0 + q + 0] = v.x; t[r][c0 + q + 1] = v.y;
    t[r][c0 + q + 2] = v.z; t[r][c0 + q + 3] = v.w;
  }
  __syncthreads();
  const int n = n0 + r;
  const int j = (n >> 4) * 64 + g * 16 + (n & 15);
  short8 o0, o1;
  #pragma unroll
  for (int q = 0; q < 8; q++) o0[q] = f2b(t[c0 + q][r]);
  #pragma unroll
  for (int q = 0; q < 8; q++) o1[q] = f2b(t[c0 + 8 + q][r]);
  short* d = dst + (size_t)j * K + k0 + c0;
  *(short8*)d = o0;
  *((short8*)d + 1) = o1;
}

__global__ void transpose_conv(const float* __restrict__ src, short* __restrict__ dst,
                               int N, int K) {
  __shared__ float t[64][65];
  const int k0 = blockIdx.x * 64, n0 = blockIdx.y * 64;
  const int tid = threadIdx.x;           // 256
  const int r = tid >> 2, c0 = (tid & 3) * 16;
  const float* s = src + (size_t)(k0 + r) * N + n0 + c0;
  #pragma unroll
  for (int q = 0; q < 16; q += 4) {
    float4 v = *(const float4*)(s + q);
    t[r][c0 + q + 0] = v.x; t[r][c0 + q + 1] = v.y;
    t[r][c0 + q + 2] = v.z; t[r][c0 + q + 3] = v.w;
  }
  __syncthreads();
  const int n = n0 + r;
  short8 o0, o1;
  #pragma unroll
  for (int q = 0; q < 8; q++) o0[q] = f2b(t[c0 + q][r]);
  #pragma unroll
  for (int q = 0; q < 8; q++) o1[q] = f2b(t[c0 + 8 + q][r]);
  short* d = dst + (size_t)n * K + k0 + c0;
  *(short8*)d = o0;
  *((short8*)d + 1) = o1;
}

__global__ void conv_plain(const float* __restrict__ src, short* __restrict__ dst, int n8) {
  const int id = blockIdx.x * blockDim.x + threadIdx.x;
  if (id >= n8) return;
  const float4* p = (const float4*)(src + (size_t)id * 8);
  float4 a = p[0], b = p[1];
  short8 o;
  o[0] = f2b(a.x); o[1] = f2b(a.y); o[2] = f2b(a.z); o[3] = f2b(a.w);
  o[4] = f2b(b.x); o[5] = f2b(b.y); o[6] = f2b(b.z); o[7] = f2b(b.w);
  *(short8*)(dst + (size_t)id * 8) = o;
}

__global__ void bp_init(const float* __restrict__ bm2, float* __restrict__ bp) {
  bp[threadIdx.x] = bm2[threadIdx.x];
}
__global__ void bp_acc(const float* __restrict__ bm1, const float* __restrict__ Wm2,
                       float* __restrict__ bp) {
  const int o = threadIdx.x;
  const int k0 = blockIdx.x * 64;
  float s = 0.f;
  #pragma unroll 4
  for (int k = 0; k < 64; k++) s += bm1[k0 + k] * Wm2[(size_t)(k0 + k) * 256 + o];
  atomicAdd(&bp[o], s);
}

// ---------------- small GEMM (m97-style 128x128) ----------------
template <int EPI>
__global__ __launch_bounds__(256) void gemm_bt(
    const short* __restrict__ A, const short* __restrict__ Bt, int K,
    short* __restrict__ Cb, int ldc,
    float* __restrict__ outp, const float* __restrict__ bpv) {
  __shared__ __align__(16) short sA[128 * 32];
  __shared__ __align__(16) short sB[128 * 32];
  const int tid = threadIdx.x;
  const int lane = tid & 63;
  const int wave = tid >> 6;
  const int wm = wave >> 1, wn = wave & 1;
  const int bm = blockIdx.x, bn = blockIdx.y;
  const int lr = lane & 15, lq = lane >> 4;

  f32x4 acc[4][4] = {};

  const short* pA = A + ((size_t)(bm * 128 + (tid >> 2))) * K + (tid & 3) * 8;
  const short* pB = Bt + ((size_t)(bn * 128 + (tid >> 2))) * K + (tid & 3) * 8;
  short* lA = sA + tid * 8;
  short* lB = sB + tid * 8;
  const int aoff = (wm * 64 + lr) * 32 + lq * 8;
  const int boff = (wn * 64 + lr) * 32 + lq * 8;

  for (int k0 = 0; k0 < K; k0 += 32) {
    gload16(pA + k0, lA);
    gload16(pA + (size_t)64 * K + k0, lA + 2048);
    gload16(pB + k0, lB);
    gload16(pB + (size_t)64 * K + k0, lB + 2048);
    __syncthreads();
    short8 af[4], bv[4];
    #pragma unroll
    for (int m = 0; m < 4; m++) af[m] = *(const short8*)&sA[aoff + m * 512];
    #pragma unroll
    for (int n = 0; n < 4; n++) bv[n] = *(const short8*)&sB[boff + n * 512];
    #pragma unroll
    for (int m = 0; m < 4; m++)
      #pragma unroll
      for (int n = 0; n < 4; n++)
        acc[m][n] = __builtin_amdgcn_mfma_f32_16x16x32_bf16(af[m], bv[n], acc[m][n], 0, 0, 0);
    __syncthreads();
  }

  const int crow0 = bm * 128 + wm * 64 + lq * 4;
  const int ccol0 = bn * 128 + wn * 64 + lr;

  if constexpr (EPI == 0) {
    #pragma unroll
    for (int m = 0; m < 4; m++)
      #pragma unroll
      for (int r = 0; r < 4; r++) {
        const int row = crow0 + m * 16 + r;
        #pragma unroll
        for (int n = 0; n < 4; n++)
          Cb[(size_t)row * ldc + ccol0 + n * 16] = f2b(acc[m][n][r]);
      }
  } else {
    float bvv[4];
    #pragma unroll
    for (int n = 0; n < 4; n++) bvv[n] = bpv[ccol0 + n * 16];
    #pragma unroll
    for (int m = 0; m < 4; m++)
      #pragma unroll
      for (int r = 0; r < 4; r++) {
        const int row = crow0 + m * 16 + r;
        #pragma unroll
        for (int n = 0; n < 4; n++)
          outp[(size_t)row * 256 + ccol0 + n * 16] = acc[m][n][r] + bvv[n];
      }
  }
}

// ------- 128x128 4-phase LSTM GEMM, 2 blocks/CU (T2+T3+T4+T5 + TLP) -------
// A [M][K] bf16, Bt [4096][K] bf16 gate-interleaved B^T. 512 thr, 8 waves 4Mx2N;
// per-wave 32 rows x 64 phys cols (= all 4 gates of 16 logical n).
// LDS 64KB: sA/sB [2 dbuf][2 half][64 rows][64 cols], XOR chunk swizzle.
// Counted vmcnt(2) at Q2/Q4 only; raw s_barrier; setprio around MFMA.
// WAR safety: each half re-staged >=1 barrier-phase after its last ds_read.

#define STA(buf, h, kt) gload16(gA + (size_t)(h) * 64 * K + (size_t)(kt) * 64 + rofs, \
                                &sA[buf][h][tid * 8])
#define STB(buf, h, kt) gload16(gB + (size_t)(h) * 64 * K + (size_t)(kt) * 64 + rofs, \
                                &sB[buf][h][tid * 8])

#define LDB(buf) {                                                \
    const short* bb = &sB[buf][wn][lr * 64];                      \
    _Pragma("unroll") for (int n = 0; n < 4; n++) {               \
      bv[n][0] = *(const short8*)(bb + n * 1024 + sw0);           \
      bv[n][1] = *(const short8*)(bb + n * 1024 + sw1); } }

#define LDA_(buf, mf, av) {                                       \
    const short* ab = &sA[buf][wm >> 1][((wm & 1) * 32 + (mf) * 16 + lr) * 64]; \
    av[0] = *(const short8*)(ab + sw0);                           \
    av[1] = *(const short8*)(ab + sw1); }

#define MM(mf, av) {                                              \
    __builtin_amdgcn_s_setprio(1);                                \
    _Pragma("unroll") for (int n = 0; n < 4; n++) {               \
      acc[mf][n] = __builtin_amdgcn_mfma_f32_16x16x32_bf16(av[0], bv[n][0], acc[mf][n], 0, 0, 0); \
      acc[mf][n] = __builtin_amdgcn_mfma_f32_16x16x32_bf16(av[1], bv[n][1], acc[mf][n], 0, 0, 0); } \
    __builtin_amdgcn_s_setprio(0); }

#define BAR() asm volatile("s_barrier" ::: "memory")
#define VM2() asm volatile("s_waitcnt vmcnt(2)" ::: "memory")

__global__ __launch_bounds__(512, 4) void gemm4_lstm(
    const short* __restrict__ A, const short* __restrict__ Bt, const int K,
    const float* __restrict__ cprev, float* __restrict__ hout,
    float* __restrict__ cout, short* __restrict__ anext, const int ldan,
    const float* __restrict__ mask,
    const float* __restrict__ bF, const float* __restrict__ bI,
    const float* __restrict__ bC, const float* __restrict__ bO) {
  __shared__ __align__(16) short sA[2][2][4096];
  __shared__ __align__(16) short sB[2][2][4096];
  const int tid = threadIdx.x;
  const int lane = tid & 63, wid = tid >> 6;
  const int wm = wid >> 1, wn = wid & 1;     // 4M x 2N waves
  const int lr = lane & 15, lq = lane >> 4;
  const int bm = blockIdx.x, bn = blockIdx.y;

  const int NT = K >> 6;        // BK=64 tiles
  const int NIT = NT >> 1;      // 2 K-tiles per iteration (NT even)

  // staging: 1 gload16 per thread per half; inverse-swizzled source chunk
  const int r0 = tid >> 3;                  // lds row [0,64)
  const int csw = (tid & 7) ^ (r0 & 7);     // swizzled 16B chunk
  const size_t rofs = (size_t)r0 * K + csw * 8;
  const short* gA = A + (size_t)bm * 128 * K;
  const short* gB = Bt + (size_t)bn * 128 * K;

  // ds_read swizzled k-chunk offsets (element units)
  const int sw0 = ((lq) ^ (lr & 7)) * 8;
  const int sw1 = ((4 + lq) ^ (lr & 7)) * 8;

  f32x4 acc[2][4] = {};
  short8 bv[4][2];

  // prologue: buf0 = tile0 (full), buf1 = tile1 (B halves only)
  STB(0, 0, 0); STB(0, 1, 0); STA(0, 0, 0); STA(0, 1, 0);
  STB(1, 0, 1); STB(1, 1, 1);
  VM2(); BAR();

  for (int it = 0; it < NIT; ++it) {
    const int k1 = 2 * it + 1;
    int t2 = 2 * it + 2; if (t2 >= NT) t2 = 0;
    int t3 = 2 * it + 3; if (t3 >= NT) t3 = 1;
    // Q1: buf0 mf0; stage buf1.A(k1) (buf1.A last read prev Q4)
    { short8 av[2]; LDB(0); LDA_(0, 0, av); STA(1, 0, k1); STA(1, 1, k1);
      BAR(); MM(0, av); BAR(); }
    // Q2: buf0 mf1; stage buf0.B(t2) (read Q1); vmcnt(2) -> buf1 fully landed
    { short8 av[2]; LDA_(0, 1, av); STB(0, 0, t2); STB(0, 1, t2);
      VM2(); BAR(); MM(1, av); BAR(); }
    // Q3: buf1 mf0; stage buf0.A(t2) (read Q2)
    { short8 av[2]; LDB(1); LDA_(1, 0, av); STA(0, 0, t2); STA(0, 1, t2);
      BAR(); MM(0, av); BAR(); }
    // Q4: buf1 mf1; stage buf1.B(t3) (read Q3); vmcnt(2) -> buf0 (t2) landed
    { short8 av[2]; LDA_(1, 1, av); STB(1, 0, t3); STB(1, 1, t3);
      VM2(); BAR(); MM(1, av); BAR(); }
  }

  // ---- LSTM cell epilogue (acc[mf][gate]) ----
  const int n = bn * 32 + wn * 16 + lr;     // logical hidden index
  const float bf_ = bF[n], bi_ = bI[n], bc_ = bC[n], bo_ = bO[n];
  const int row0 = bm * 128 + wm * 32 + lq * 4;

  float cp[2][4], mk[2][4];
  #pragma unroll
  for (int mf = 0; mf < 2; mf++)
    #pragma unroll
    for (int rr = 0; rr < 4; rr++) {
      const size_t idx = (size_t)(row0 + mf * 16 + rr) * 1024 + n;
      cp[mf][rr] = cprev[idx];
      mk[mf][rr] = mask ? mask[idx] : 1.0f;
    }
  #pragma unroll
  for (int mf = 0; mf < 2; mf++) {
    #pragma unroll
    for (int rr = 0; rr < 4; rr++) {
      const int row = row0 + mf * 16 + rr;
      const size_t idx = (size_t)row * 1024 + n;
      const float fg = sigm(acc[mf][0][rr] + bf_);
      const float ig = sigm(acc[mf][1][rr] + bi_);
      const float cg = tanh_(acc[mf][2][rr] + bc_);
      const float og = sigm(acc[mf][3][rr] + bo_);
      const float cn = fg * cp[mf][rr] + ig * cg;
      const float hn = og * tanh_(cn);
      cout[idx] = cn;
      hout[idx] = hn;
      anext[(size_t)row * ldan + n] = f2b(hn * mk[mf][rr]);
    }
  }
}

// ---------------- launch ----------------

extern "C" void kernel_launch(void* const* d_in, const int* in_sizes, int n_in,
                              void* d_out, int out_size, void* d_ws, size_t ws_size,
                              hipStream_t stream) {
  (void)in_sizes; (void)n_in; (void)out_size; (void)ws_size;
  const float* x   = (const float*)d_in[0];
  const float* h0  = (const float*)d_in[1];
  const float* h1  = (const float*)d_in[2];
  const float* c0  = (const float*)d_in[3];
  const float* c1  = (const float*)d_in[4];
  const float* m0  = (const float*)d_in[5];
  const float* m1  = (const float*)d_in[6];
  const float* Wf0 = (const float*)d_in[7];  const float* bf0 = (const float*)d_in[8];
  const float* Wi0 = (const float*)d_in[9];  const float* bi0 = (const float*)d_in[10];
  const float* Wc0 = (const float*)d_in[11]; const float* bc0 = (const float*)d_in[12];
  const float* Wo0 = (const float*)d_in[13]; const float* bo0 = (const float*)d_in[14];
  const float* Wf1 = (const float*)d_in[15]; const float* bf1 = (const float*)d_in[16];
  const float* Wi1 = (const float*)d_in[17]; const float* bi1 = (const float*)d_in[18];
  const float* Wc1 = (const float*)d_in[19]; const float* bc1 = (const float*)d_in[20];
  const float* Wo1 = (const float*)d_in[21]; const float* bo1 = (const float*)d_in[22];
  const float* Wm1 = (const float*)d_in[23]; const float* bm1 = (const float*)d_in[24];
  const float* Wm2 = (const float*)d_in[25]; const float* bm2 = (const float*)d_in[26];

  float* dout  = (float*)d_out;
  float* out_o = dout;                    // [8192,256]
  float* h0n   = dout + 2097152;          // [8192,1024]
  float* h1n   = h0n + 8388608;
  float* c0n   = h1n + 8388608;
  float* c1n   = c0n + 8388608;

  char* ws = (char*)d_ws;
  short* A0   = (short*)(ws);              // 8192x1536 bf16
  short* A1   = (short*)(ws + 25165824);   // 8192x2048
  short* A2   = (short*)(ws + 58720256);   // 8192x1024
  short* WT0  = (short*)(ws + 75497472);   // 4096x1536 (gate-interleaved B^T)
  short* WT1  = (short*)(ws + 88080384);   // 4096x2048
  short* Wm1b = (short*)(ws + 104857600);  // 1024x2048
  short* Wm2T = (short*)(ws + 109051904);  // 256x2048
  short* WpT  = (short*)(ws + 110100480);  // 256x1024
  float* bp   = (float*)(ws + 110624768);  // 256

  // ---- prep ----
  conv_A0<<<dim3(8192), dim3(192), 0, stream>>>(x, h0, m0, A0);
  conv_A1hi<<<dim3(8192), dim3(128), 0, stream>>>(h1, m1, A1);
  transpose_conv4<<<dim3(24, 16, 4), dim3(256), 0, stream>>>(Wf0, Wi0, Wc0, Wo0, WT0, 1024, 1536);
  transpose_conv4<<<dim3(32, 16, 4), dim3(256), 0, stream>>>(Wf1, Wi1, Wc1, Wo1, WT1, 1024, 2048);
  conv_plain<<<dim3(1024), dim3(256), 0, stream>>>(Wm1, Wm1b, 262144);
  transpose_conv<<<dim3(32, 4), dim3(256), 0, stream>>>(Wm2, Wm2T, 256, 2048);
  bp_init<<<dim3(1), dim3(256), 0, stream>>>(bm2, bp);
  bp_acc<<<dim3(32), dim3(256), 0, stream>>>(bm1, Wm2, bp);

  // ---- collapsed MLP weight: WpT = (Wm1@Wm2)^T ----
  gemm_bt<0><<<dim3(2, 8), dim3(256), 0, stream>>>(
      Wm2T, Wm1b, 2048, WpT, 1024, nullptr, nullptr);

  // ---- layer 0: h0n,c0n + A1[:, :1024] = bf16(h0n*m0) ----
  gemm4_lstm<<<dim3(64, 32), dim3(512), 0, stream>>>(
      A0, WT0, 1536, c0, h0n, c0n, A1, 2048, m0, bf0, bi0, bc0, bo0);

  // ---- layer 1: h1n,c1n + A2 = bf16(h1n) ----
  gemm4_lstm<<<dim3(64, 32), dim3(512), 0, stream>>>(
      A1, WT1, 2048, c1, h1n, c1n, A2, 1024, nullptr, bf1, bi1, bc1, bo1);

  // ---- output: out = h1n @ Wp + bp ----
  gemm_bt<1><<<dim3(64, 2), dim3(256), 0, stream>>>(
      A2, WpT, 1024, nullptr, 0, out_o, bp);
}

// Round 6
// 399.562 us; speedup vs baseline: 1.0139x; 1.0139x over previous
//
#include <hip/hip_runtime.h>
#include <hip/hip_bf16.h>
#include <cstdint>
#include <cstddef>

#define DI __device__ __forceinline__

typedef __attribute__((ext_vector_type(8))) short short8;
typedef __attribute__((ext_vector_type(4))) float f32x4;

static constexpr int Bb = 8192, Dd = 512, Hh = 1024;

DI short f2b(float f) {
  union { __hip_bfloat16 h; short s; } u;
  u.h = __float2bfloat16(f);
  return u.s;
}

// fast sigmoid/tanh: v_exp + v_rcp (1-ulp rcp; output checked at bf16 level)
DI float sigm(float x) {
  float e = __builtin_amdgcn_exp2f(-1.4426950408889634f * x);
  return __builtin_amdgcn_rcpf(1.0f + e);
}
DI float tanh_(float x) {
  float xc = fminf(fmaxf(x, -20.0f), 20.0f);
  float e = __builtin_amdgcn_exp2f(-2.8853900817779268f * xc);  // exp(-2x)
  return (1.0f - e) * __builtin_amdgcn_rcpf(1.0f + e);
}

DI void gload16(const void* g, void* l) {
  __builtin_amdgcn_global_load_lds(
      (const __attribute__((address_space(1))) uint32_t*)g,
      (__attribute__((address_space(3))) uint32_t*)l, 16, 0, 0);
}

// ---------------- prep kernels ----------------

__global__ void conv_A0(const float* __restrict__ x, const float* __restrict__ h0,
                        const float* __restrict__ m0, short* __restrict__ A0) {
  const int row = blockIdx.x, t = threadIdx.x;  // block=192
  float v[8];
  if (t < 64) {
    const float4* p = (const float4*)(x + (size_t)row * Dd + t * 8);
    float4 a = p[0], b = p[1];
    v[0] = a.x; v[1] = a.y; v[2] = a.z; v[3] = a.w;
    v[4] = b.x; v[5] = b.y; v[6] = b.z; v[7] = b.w;
  } else {
    const int j = t * 8 - 512;
    const float4* ph = (const float4*)(h0 + (size_t)row * Hh + j);
    const float4* pm = (const float4*)(m0 + (size_t)row * Hh + j);
    float4 a = ph[0], b = ph[1], ma = pm[0], mb = pm[1];
    v[0] = a.x * ma.x; v[1] = a.y * ma.y; v[2] = a.z * ma.z; v[3] = a.w * ma.w;
    v[4] = b.x * mb.x; v[5] = b.y * mb.y; v[6] = b.z * mb.z; v[7] = b.w * mb.w;
  }
  short8 o;
  #pragma unroll
  for (int q = 0; q < 8; q++) o[q] = f2b(v[q]);
  *(short8*)(A0 + (size_t)row * 1536 + t * 8) = o;
}

__global__ void conv_A1hi(const float* __restrict__ h1, const float* __restrict__ m1,
                          short* __restrict__ A1) {
  const int row = blockIdx.x, t = threadIdx.x;  // block=128
  const int j = t * 8;
  const float4* ph = (const float4*)(h1 + (size_t)row * Hh + j);
  const float4* pm = (const float4*)(m1 + (size_t)row * Hh + j);
  float4 a = ph[0], b = ph[1], ma = pm[0], mb = pm[1];
  float v[8] = {a.x * ma.x, a.y * ma.y, a.z * ma.z, a.w * ma.w,
                b.x * mb.x, b.y * mb.y, b.z * mb.z, b.w * mb.w};
  short8 o;
  #pragma unroll
  for (int q = 0; q < 8; q++) o[q] = f2b(v[q]);
  *(short8*)(A1 + (size_t)row * 2048 + 1024 + j) = o;
}

// 4-gate fused transpose+convert
__global__ void transpose_conv4(const float* __restrict__ s0, const float* __restrict__ s1,
                                const float* __restrict__ s2, const float* __restrict__ s3,
                                short* __restrict__ dst, int N, int K) {
  __shared__ float t[64][65];
  const int g = blockIdx.z;
  const float* src = (g == 0) ? s0 : (g == 1) ? s1 : (g == 2) ? s2 : s3;
  const int k0 = blockIdx.x * 64, n0 = blockIdx.y * 64;
  const int tid = threadIdx.x;           // 256
  const int r = tid >> 2, c0 = (tid & 3) * 16;
  const float* s = src + (size_t)(k0 + r) * N + n0 + c0;
  #pragma unroll
  for (int q = 0; q < 16; q += 4) {
    float4 v = *(const float4*)(s + q);
    t[r][c0 + q + 0] = v.x; t[r][c0 + q + 1] = v.y;
    t[r][c0 + q + 2] = v.z; t[r][c0 + q + 3] = v.w;
  }
  __syncthreads();
  const int n = n0 + r;
  const int j = (n >> 4) * 64 + g * 16 + (n & 15);
  short8 o0, o1;
  #pragma unroll
  for (int q = 0; q < 8; q++) o0[q] = f2b(t[c0 + q][r]);
  #pragma unroll
  for (int q = 0; q < 8; q++) o1[q] = f2b(t[c0 + 8 + q][r]);
  short* d = dst + (size_t)j * K + k0 + c0;
  *(short8*)d = o0;
  *((short8*)d + 1) = o1;
}

__global__ void transpose_conv(const float* __restrict__ src, short* __restrict__ dst,
                               int N, int K) {
  __shared__ float t[64][65];
  const int k0 = blockIdx.x * 64, n0 = blockIdx.y * 64;
  const int tid = threadIdx.x;           // 256
  const int r = tid >> 2, c0 = (tid & 3) * 16;
  const float* s = src + (size_t)(k0 + r) * N + n0 + c0;
  #pragma unroll
  for (int q = 0; q < 16; q += 4) {
    float4 v = *(const float4*)(s + q);
    t[r][c0 + q + 0] = v.x; t[r][c0 + q + 1] = v.y;
    t[r][c0 + q + 2] = v.z; t[r][c0 + q + 3] = v.w;
  }
  __syncthreads();
  const int n = n0 + r;
  short8 o0, o1;
  #pragma unroll
  for (int q = 0; q < 8; q++) o0[q] = f2b(t[c0 + q][r]);
  #pragma unroll
  for (int q = 0; q < 8; q++) o1[q] = f2b(t[c0 + 8 + q][r]);
  short* d = dst + (size_t)n * K + k0 + c0;
  *(short8*)d = o0;
  *((short8*)d + 1) = o1;
}

__global__ void conv_plain(const float* __restrict__ src, short* __restrict__ dst, int n8) {
  const int id = blockIdx.x * blockDim.x + threadIdx.x;
  if (id >= n8) return;
  const float4* p = (const float4*)(src + (size_t)id * 8);
  float4 a = p[0], b = p[1];
  short8 o;
  o[0] = f2b(a.x); o[1] = f2b(a.y); o[2] = f2b(a.z); o[3] = f2b(a.w);
  o[4] = f2b(b.x); o[5] = f2b(b.y); o[6] = f2b(b.z); o[7] = f2b(b.w);
  *(short8*)(dst + (size_t)id * 8) = o;
}

__global__ void bp_init(const float* __restrict__ bm2, float* __restrict__ bp) {
  bp[threadIdx.x] = bm2[threadIdx.x];
}
__global__ void bp_acc(const float* __restrict__ bm1, const float* __restrict__ Wm2,
                       float* __restrict__ bp) {
  const int o = threadIdx.x;
  const int k0 = blockIdx.x * 64;
  float s = 0.f;
  #pragma unroll 4
  for (int k = 0; k < 64; k++) s += bm1[k0 + k] * Wm2[(size_t)(k0 + k) * 256 + o];
  atomicAdd(&bp[o], s);
}

// ---------------- small GEMM (m97-style 128x128) ----------------
template <int EPI>
__global__ __launch_bounds__(256) void gemm_bt(
    const short* __restrict__ A, const short* __restrict__ Bt, int K,
    short* __restrict__ Cb, int ldc,
    float* __restrict__ outp, const float* __restrict__ bpv) {
  __shared__ __align__(16) short sA[128 * 32];
  __shared__ __align__(16) short sB[128 * 32];
  const int tid = threadIdx.x;
  const int lane = tid & 63;
  const int wave = tid >> 6;
  const int wm = wave >> 1, wn = wave & 1;
  const int bm = blockIdx.x, bn = blockIdx.y;
  const int lr = lane & 15, lq = lane >> 4;

  f32x4 acc[4][4] = {};

  const short* pA = A + ((size_t)(bm * 128 + (tid >> 2))) * K + (tid & 3) * 8;
  const short* pB = Bt + ((size_t)(bn * 128 + (tid >> 2))) * K + (tid & 3) * 8;
  short* lA = sA + tid * 8;
  short* lB = sB + tid * 8;
  const int aoff = (wm * 64 + lr) * 32 + lq * 8;
  const int boff = (wn * 64 + lr) * 32 + lq * 8;

  for (int k0 = 0; k0 < K; k0 += 32) {
    gload16(pA + k0, lA);
    gload16(pA + (size_t)64 * K + k0, lA + 2048);
    gload16(pB + k0, lB);
    gload16(pB + (size_t)64 * K + k0, lB + 2048);
    __syncthreads();
    short8 af[4], bv[4];
    #pragma unroll
    for (int m = 0; m < 4; m++) af[m] = *(const short8*)&sA[aoff + m * 512];
    #pragma unroll
    for (int n = 0; n < 4; n++) bv[n] = *(const short8*)&sB[boff + n * 512];
    #pragma unroll
    for (int m = 0; m < 4; m++)
      #pragma unroll
      for (int n = 0; n < 4; n++)
        acc[m][n] = __builtin_amdgcn_mfma_f32_16x16x32_bf16(af[m], bv[n], acc[m][n], 0, 0, 0);
    __syncthreads();
  }

  const int crow0 = bm * 128 + wm * 64 + lq * 4;
  const int ccol0 = bn * 128 + wn * 64 + lr;

  if constexpr (EPI == 0) {
    #pragma unroll
    for (int m = 0; m < 4; m++)
      #pragma unroll
      for (int r = 0; r < 4; r++) {
        const int row = crow0 + m * 16 + r;
        #pragma unroll
        for (int n = 0; n < 4; n++)
          Cb[(size_t)row * ldc + ccol0 + n * 16] = f2b(acc[m][n][r]);
      }
  } else {
    float bvv[4];
    #pragma unroll
    for (int n = 0; n < 4; n++) bvv[n] = bpv[ccol0 + n * 16];
    #pragma unroll
    for (int m = 0; m < 4; m++)
      #pragma unroll
      for (int r = 0; r < 4; r++) {
        const int row = crow0 + m * 16 + r;
        #pragma unroll
        for (int n = 0; n < 4; n++)
          outp[(size_t)row * 256 + ccol0 + n * 16] = acc[m][n][r] + bvv[n];
      }
  }
}

// ------- 256x256 8-phase LSTM GEMM, 16 waves (4Mx4N), 4 waves/SIMD -------
// A [M][K] bf16, Bt [4096][K] bf16 gate-interleaved B^T. 1024 thr.
// Per-wave out 64x64 (acc[4][4] = 64 f32) so total regs fit 4 waves/SIMD.
// m-frags interleaved across phases: phase q handles rows q*64 + wr*16,
// so A-half h is read only in phases 2h+1,2h+2 -> legal stage rotation:
//   buf0 @ {P2:B0, P3:A0, P4:B1, P5:A1}, buf1 @ {P6:B0, P7:A0, P8:B1, nextP1:A1}
// 1 gload16/thread per half (16KB); vmcnt(3) at P4/P8 (counted, never 0).
// LDS 128KB: sA/sB [2 buf][2 half][128*64], XOR chunk swizzle both sides.

#define STA(buf, h, kt) gload16(gA + (size_t)(h) * 128 * K + (size_t)(kt) * 64 + rofs, \
                                &sA[buf][h][tid * 8])
#define STB(buf, h, kt) gload16(gB + (size_t)(h) * 128 * K + (size_t)(kt) * 64 + rofs, \
                                &sB[buf][h][tid * 8])

#define LDB(buf) {                                                \
    const short* bb = &sB[buf][wc >> 1][((wc & 1) * 64 + lr) * 64]; \
    _Pragma("unroll") for (int n = 0; n < 4; n++) {               \
      bv[n][0] = *(const short8*)(bb + n * 1024 + sw0);           \
      bv[n][1] = *(const short8*)(bb + n * 1024 + sw1); } }

#define LDA_(buf, q, av) {                                        \
    const short* ab = &sA[buf][(q) >> 1][(((q) & 1) * 64 + wr * 16 + lr) * 64]; \
    av[0] = *(const short8*)(ab + sw0);                           \
    av[1] = *(const short8*)(ab + sw1); }

#define MM(q, av) {                                               \
    __builtin_amdgcn_s_setprio(1);                                \
    _Pragma("unroll") for (int n = 0; n < 4; n++) {               \
      acc[q][n] = __builtin_amdgcn_mfma_f32_16x16x32_bf16(av[0], bv[n][0], acc[q][n], 0, 0, 0); \
      acc[q][n] = __builtin_amdgcn_mfma_f32_16x16x32_bf16(av[1], bv[n][1], acc[q][n], 0, 0, 0); } \
    __builtin_amdgcn_s_setprio(0); }

#define BAR() asm volatile("s_barrier" ::: "memory")
#define VM3() asm volatile("s_waitcnt vmcnt(3)" ::: "memory")

__global__ __launch_bounds__(1024, 4) void gemm16_lstm(
    const short* __restrict__ A, const short* __restrict__ Bt, const int K,
    const float* __restrict__ cprev, float* __restrict__ hout,
    float* __restrict__ cout, short* __restrict__ anext, const int ldan,
    const float* __restrict__ mask,
    const float* __restrict__ bF, const float* __restrict__ bI,
    const float* __restrict__ bC, const float* __restrict__ bO) {
  __shared__ __align__(16) short sA[2][2][8192];
  __shared__ __align__(16) short sB[2][2][8192];
  const int tid = threadIdx.x;
  const int lane = tid & 63, wid = tid >> 6;
  const int wr = wid >> 2, wc = wid & 3;        // 4M x 4N waves
  const int lr = lane & 15, lq = lane >> 4;
  const int bm = blockIdx.x, bn = blockIdx.y;

  const int NT = K >> 6;        // BK=64 tiles
  const int NIT = NT >> 1;

  // staging: 1 gload16/thread per 128x64 half; inverse-swizzled source chunk
  const int r0 = tid >> 3;                  // row in half [0,128)
  const int csw = (tid & 7) ^ (r0 & 7);     // swizzled 16B chunk
  const size_t rofs = (size_t)r0 * K + csw * 8;
  const short* gA = A + (size_t)bm * 256 * K;
  const short* gB = Bt + (size_t)bn * 256 * K;

  // ds_read swizzled k-chunk offsets (element units)
  const int sw0 = ((lq) ^ (lr & 7)) * 8;
  const int sw1 = ((4 + lq) ^ (lr & 7)) * 8;

  f32x4 acc[4][4] = {};
  short8 bv[4][2];

  // prologue: buf0 = tile0 (4 halves) + buf1 = tile1 {B0,A0,B1}
  STB(0, 0, 0); STA(0, 0, 0); STB(0, 1, 0); STA(0, 1, 0);
  STB(1, 0, 1); STA(1, 0, 1); STB(1, 1, 1);
  VM3(); BAR();

  for (int it = 0; it < NIT; ++it) {
    const int k1 = 2 * it + 1;
    int t2 = 2 * it + 2; if (t2 >= NT) t2 = 0;
    int t3 = 2 * it + 3; if (t3 >= NT) t3 = 1;
    // P1: buf0 q0 (A-half0); complete buf1 with A1(k1)
    { short8 av[2]; LDB(0); LDA_(0, 0, av); STA(1, 1, k1); BAR(); MM(0, av); BAR(); }
    // P2: buf0 q1 (A-half0); stage buf0.B0(t2) (B read done P1)
    { short8 av[2]; LDA_(0, 1, av); STB(0, 0, t2); BAR(); MM(1, av); BAR(); }
    // P3: buf0 q2 (A-half1); stage buf0.A0(t2) (A-half0 read done P2)
    { short8 av[2]; LDA_(0, 2, av); STA(0, 0, t2); BAR(); MM(2, av); BAR(); }
    // P4: buf0 q3; stage buf0.B1(t2); vmcnt(3) -> buf1 fully landed
    { short8 av[2]; LDA_(0, 3, av); STB(0, 1, t2); VM3(); BAR(); MM(3, av); BAR(); }
    // P5: buf1 q0; stage buf0.A1(t2) (A-half1 read done P4)
    { short8 av[2]; LDB(1); LDA_(1, 0, av); STA(0, 1, t2); BAR(); MM(0, av); BAR(); }
    // P6: buf1 q1; stage buf1.B0(t3)
    { short8 av[2]; LDA_(1, 1, av); STB(1, 0, t3); BAR(); MM(1, av); BAR(); }
    // P7: buf1 q2; stage buf1.A0(t3) (buf1 A-half0 read done P6)
    { short8 av[2]; LDA_(1, 2, av); STA(1, 0, t3); BAR(); MM(2, av); BAR(); }
    // P8: buf1 q3; stage buf1.B1(t3); vmcnt(3) -> buf0 (t2) fully landed
    { short8 av[2]; LDA_(1, 3, av); STB(1, 1, t3); VM3(); BAR(); MM(3, av); BAR(); }
  }

  // ---- LSTM cell epilogue (acc[q][gate]): fast math + pipelined prefetch ----
  const int n = (bn * 4 + wc) * 16 + lr;     // logical hidden index [0,1024)
  const float bf_ = bF[n], bi_ = bI[n], bc_ = bC[n], bo_ = bO[n];
  const int row0 = bm * 256 + wr * 16 + lq * 4;

  float cp[4], mk[4], cpn[4], mkn[4];
  #pragma unroll
  for (int rr = 0; rr < 4; rr++) {
    const size_t idx = (size_t)(row0 + rr) * 1024 + n;
    cp[rr] = cprev[idx];
    mk[rr] = mask ? mask[idx] : 1.0f;
  }
  #pragma unroll
  for (int q = 0; q < 4; q++) {
    if (q < 3) {
      #pragma unroll
      for (int rr = 0; rr < 4; rr++) {
        const size_t idx2 = (size_t)(row0 + (q + 1) * 64 + rr) * 1024 + n;
        cpn[rr] = cprev[idx2];
        mkn[rr] = mask ? mask[idx2] : 1.0f;
      }
    }
    #pragma unroll
    for (int rr = 0; rr < 4; rr++) {
      const int row = row0 + q * 64 + rr;
      const size_t idx = (size_t)row * 1024 + n;
      const float fg = sigm(acc[q][0][rr] + bf_);
      const float ig = sigm(acc[q][1][rr] + bi_);
      const float cg = tanh_(acc[q][2][rr] + bc_);
      const float og = sigm(acc[q][3][rr] + bo_);
      const float cn = fg * cp[rr] + ig * cg;
      const float hn = og * tanh_(cn);
      cout[idx] = cn;
      hout[idx] = hn;
      anext[(size_t)row * ldan + n] = f2b(hn * mk[rr]);
    }
    #pragma unroll
    for (int rr = 0; rr < 4; rr++) { cp[rr] = cpn[rr]; mk[rr] = mkn[rr]; }
  }
}

// ---------------- launch ----------------

extern "C" void kernel_launch(void* const* d_in, const int* in_sizes, int n_in,
                              void* d_out, int out_size, void* d_ws, size_t ws_size,
                              hipStream_t stream) {
  (void)in_sizes; (void)n_in; (void)out_size; (void)ws_size;
  const float* x   = (const float*)d_in[0];
  const float* h0  = (const float*)d_in[1];
  const float* h1  = (const float*)d_in[2];
  const float* c0  = (const float*)d_in[3];
  const float* c1  = (const float*)d_in[4];
  const float* m0  = (const float*)d_in[5];
  const float* m1  = (const float*)d_in[6];
  const float* Wf0 = (const float*)d_in[7];  const float* bf0 = (const float*)d_in[8];
  const float* Wi0 = (const float*)d_in[9];  const float* bi0 = (const float*)d_in[10];
  const float* Wc0 = (const float*)d_in[11]; const float* bc0 = (const float*)d_in[12];
  const float* Wo0 = (const float*)d_in[13]; const float* bo0 = (const float*)d_in[14];
  const float* Wf1 = (const float*)d_in[15]; const float* bf1 = (const float*)d_in[16];
  const float* Wi1 = (const float*)d_in[17]; const float* bi1 = (const float*)d_in[18];
  const float* Wc1 = (const float*)d_in[19]; const float* bc1 = (const float*)d_in[20];
  const float* Wo1 = (const float*)d_in[21]; const float* bo1 = (const float*)d_in[22];
  const float* Wm1 = (const float*)d_in[23]; const float* bm1 = (const float*)d_in[24];
  const float* Wm2 = (const float*)d_in[25]; const float* bm2 = (const float*)d_in[26];

  float* dout  = (float*)d_out;
  float* out_o = dout;                    // [8192,256]
  float* h0n   = dout + 2097152;          // [8192,1024]
  float* h1n   = h0n + 8388608;
  float* c0n   = h1n + 8388608;
  float* c1n   = c0n + 8388608;

  char* ws = (char*)d_ws;
  short* A0   = (short*)(ws);              // 8192x1536 bf16
  short* A1   = (short*)(ws + 25165824);   // 8192x2048
  short* A2   = (short*)(ws + 58720256);   // 8192x1024
  short* WT0  = (short*)(ws + 75497472);   // 4096x1536 (gate-interleaved B^T)
  short* WT1  = (short*)(ws + 88080384);   // 4096x2048
  short* Wm1b = (short*)(ws + 104857600);  // 1024x2048
  short* Wm2T = (short*)(ws + 109051904);  // 256x2048
  short* WpT  = (short*)(ws + 110100480);  // 256x1024
  float* bp   = (float*)(ws + 110624768);  // 256

  // ---- prep ----
  conv_A0<<<dim3(8192), dim3(192), 0, stream>>>(x, h0, m0, A0);
  conv_A1hi<<<dim3(8192), dim3(128), 0, stream>>>(h1, m1, A1);
  transpose_conv4<<<dim3(24, 16, 4), dim3(256), 0, stream>>>(Wf0, Wi0, Wc0, Wo0, WT0, 1024, 1536);
  transpose_conv4<<<dim3(32, 16, 4), dim3(256), 0, stream>>>(Wf1, Wi1, Wc1, Wo1, WT1, 1024, 2048);
  conv_plain<<<dim3(1024), dim3(256), 0, stream>>>(Wm1, Wm1b, 262144);
  transpose_conv<<<dim3(32, 4), dim3(256), 0, stream>>>(Wm2, Wm2T, 256, 2048);
  bp_init<<<dim3(1), dim3(256), 0, stream>>>(bm2, bp);
  bp_acc<<<dim3(32), dim3(256), 0, stream>>>(bm1, Wm2, bp);

  // ---- collapsed MLP weight: WpT = (Wm1@Wm2)^T ----
  gemm_bt<0><<<dim3(2, 8), dim3(256), 0, stream>>>(
      Wm2T, Wm1b, 2048, WpT, 1024, nullptr, nullptr);

  // ---- layer 0: h0n,c0n + A1[:, :1024] = bf16(h0n*m0) ----
  gemm16_lstm<<<dim3(32, 16), dim3(1024), 0, stream>>>(
      A0, WT0, 1536, c0, h0n, c0n, A1, 2048, m0, bf0, bi0, bc0, bo0);

  // ---- layer 1: h1n,c1n + A2 = bf16(h1n) ----
  gemm16_lstm<<<dim3(32, 16), dim3(1024), 0, stream>>>(
      A1, WT1, 2048, c1, h1n, c1n, A2, 1024, nullptr, bf1, bi1, bc1, bo1);

  // ---- output: out = h1n @ Wp + bp ----
  gemm_bt<1><<<dim3(64, 2), dim3(256), 0, stream>>>(
      A2, WpT, 1024, nullptr, 0, out_o, bp);
}